// Round 6
// baseline (439.973 us; speedup 1.0000x reference)
//
#include <hip/hip_runtime.h>
#include <hip/hip_bf16.h>
#include <hip/hip_fp16.h>
#include <math.h>

typedef __hip_bfloat16 bf;

#define BB   16     // batch
#define CC   128    // channels
#define LL   4096   // H*W
#define DM   32     // d_model per chunk
#define DI   64     // d_inner
#define DSN  16     // d_state
#define GG   64     // 4 * BB sequences
#define NC   128    // scan chunks (CL=32 -> 8192 scan waves)
#define CL   32     // LL / NC
#define TLV  61     // valid output columns per k1 tile (64 loaded, 3 head)
#define NT   68     // ceil(LL / TLV)
#define XS   133    // k1 xnT row stride in dwords (odd -> conflict-free)
#define YS   35     // k1 xiS row stride in dwords
#define XROW 20     // xdbl row stride in dwords (80 B: dw0=dt01, dw1-3 pad, dw4-11=B, dw12-19=C)

__device__ __forceinline__ float bf2f(bf x) { return __bfloat162float(x); }
__device__ __forceinline__ bf f2bf(float x) { return __float2bfloat16(x); }
__device__ __forceinline__ float blo(unsigned v) { return __uint_as_float(v << 16); }
__device__ __forceinline__ float bhi(unsigned v) { return __uint_as_float(v & 0xffff0000u); }
__device__ __forceinline__ float us2f(unsigned short v) { return __uint_as_float((unsigned)v << 16); }
__device__ __forceinline__ unsigned pack2(float a, float b) {
  bf ba = f2bf(a), bb = f2bf(b);
  unsigned short ua = *(unsigned short*)&ba, ub = *(unsigned short*)&bb;
  return (unsigned)ua | ((unsigned)ub << 16);
}

#if __has_builtin(__builtin_amdgcn_exp2f)
#define EXP2F(x) __builtin_amdgcn_exp2f(x)
#else
#define EXP2F(x) exp2f(x)
#endif

__device__ __forceinline__ float sigmoidf_(float x) { return 1.0f / (1.0f + __expf(-x)); }
// fast softplus: max(x,0) + ln2 * log2(1 + exp2(-|x|*log2e))
__device__ __forceinline__ float softplus_fast(float x) {
  float t = EXP2F(-fabsf(x) * 1.44269504088896f);
  return fmaxf(x, 0.0f) + 0.69314718056f * __log2f(1.0f + t);
}
__device__ __forceinline__ void unpack8(uint4 v, float* o) {
  o[0] = blo(v.x); o[1] = bhi(v.x); o[2] = blo(v.y); o[3] = bhi(v.y);
  o[4] = blo(v.z); o[5] = bhi(v.z); o[6] = blo(v.w); o[7] = bhi(v.w);
}

// ---------------- K1: layernorm + in_proj(xi) + causal conv + silu -> u (bf16), xn (bf16) ----------------
// (unchanged)
__global__ __launch_bounds__(256, 4) void k1_ln_conv(
    const float* __restrict__ input, const float* __restrict__ ln_g, const float* __restrict__ ln_b,
    const float* __restrict__ in_proj_w, const float* __restrict__ conv_w, const float* __restrict__ conv_b,
    bf* __restrict__ u_ws, bf* __restrict__ xn_ws) {
  __shared__ unsigned ldsbuf[8960];               // union: xnT fp32 64x133dw / xiS bf16 256x35dw
  __shared__ float mu_s[64], rs_s[64];
  float* xnT = (float*)ldsbuf;
  unsigned short* xiS = (unsigned short*)ldsbuf;
  int b = blockIdx.x / NT;
  int tile = blockIdx.x - b * NT;
  int l0 = tile * TLV;
  int tid = threadIdx.x;
  const float* inb = input + (size_t)b * CC * LL;
#pragma unroll
  for (int k = 0; k < 32; k++) {
    int i = tid + k * 256;
    int j = i & 63, c = i >> 6;
    int l = l0 - 3 + j;
    xnT[j * XS + c] = (l >= 0 && l < LL) ? inb[c * LL + l] : 0.0f;
  }
  __syncthreads();
  if (tid < 64) {
    float s = 0.f, s2 = 0.f;
    for (int c = 0; c < CC; c++) { float v = xnT[tid * XS + c]; s += v; s2 = fmaf(v, v, s2); }
    float mu = s * (1.0f / CC);
    float var = s2 * (1.0f / CC) - mu * mu;
    mu_s[tid] = mu;
    rs_s[tid] = rsqrtf(var + 1e-5f);
  }
  __syncthreads();
#pragma unroll
  for (int k = 0; k < 32; k++) {
    int i = tid + k * 256;
    int j = i & 63, c = i >> 6;
    xnT[j * XS + c] = (xnT[j * XS + c] - mu_s[j]) * rs_s[j] * ln_g[c] + ln_b[c];
  }
  __syncthreads();
  for (int i = tid; i < CC * TLV; i += 256) {
    int c = i / TLV, j2 = i - c * TLV;
    int l = l0 + j2;
    if (l < LL) xn_ws[((size_t)(b * CC + c)) * LL + l] = f2bf(xnT[(j2 + 3) * XS + c]);
  }
  int g = tid >> 6, j = tid & 63;
  float xr[32];
#pragma unroll
  for (int r = 0; r < 32; r++) xr[r] = xnT[j * XS + g * DM + r];
  bool zero_col = (l0 - 3 + j < 0);
  __syncthreads();
#pragma unroll
  for (int c2 = 0; c2 < 4; c2++) {
    float acc[16];
#pragma unroll
    for (int dd = 0; dd < 16; dd++) {
      const float* w = in_proj_w + (c2 * 16 + dd) * DM;
      float a = 0.f;
#pragma unroll
      for (int r = 0; r < 32; r++) a = fmaf(xr[r], w[r], a);
      acc[dd] = zero_col ? 0.f : a;
    }
    unsigned* xo = (unsigned*)&ldsbuf[(g * 64 + j) * YS + c2 * 8];
#pragma unroll
    for (int k = 0; k < 8; k++)
      xo[k] = pack2(acc[2 * k], acc[2 * k + 1]);
  }
  __syncthreads();
  int d = j;
  float cw0 = conv_w[d * 4 + 0], cw1 = conv_w[d * 4 + 1];
  float cw2 = conv_w[d * 4 + 2], cw3 = conv_w[d * 4 + 3];
  float cb = conv_b[d];
  bf* uo = u_ws + (size_t)(g * BB + b) * LL * DI + d;
  float x3 = 0.f, x2 = 0.f, x1 = 0.f, x0 = 0.f;
  for (int jj = 0; jj < 64; jj++) {
    float xi = us2f(xiS[(g * 64 + jj) * (2 * YS) + d]);
    x3 = x2; x2 = x1; x1 = x0; x0 = xi;
    int l = l0 + jj - 3;
    if (jj >= 3 && l < LL) {
      float pre = x3 * cw0 + x2 * cw1 + x1 * cw2 + x0 * cw3 + cb;
      float uu = pre * sigmoidf_(pre);
      uo[(size_t)l * DI] = f2bf(uu);
    }
  }
}

// ---------------- K2: x_proj only -> xdbl rows (dt0,dt1,B,C packed bf16, 80 B/pos) ----------------
// (unchanged)
__global__ __launch_bounds__(256) void k2_xproj(
    const bf* __restrict__ u_ws, const float* __restrict__ x_proj_w,
    unsigned* __restrict__ xdbl) {
  __shared__ unsigned uS[256 * 33];
  int tid = threadIdx.x;
  size_t pos0 = (size_t)blockIdx.x * 256;
  const unsigned* src = (const unsigned*)u_ws + pos0 * 32;
#pragma unroll
  for (int k = 0; k < 32; k++) {
    int idx = tid + k * 256;
    uS[(idx >> 5) * 33 + (idx & 31)] = src[idx];
  }
  __syncthreads();
  float xdb[34];
#pragma unroll
  for (int e = 0; e < 34; e++) xdb[e] = 0.f;
#pragma unroll
  for (int c2 = 0; c2 < 4; c2++) {
    float f[16];
#pragma unroll
    for (int k = 0; k < 8; k++) {
      unsigned v = uS[tid * 33 + c2 * 8 + k];
      f[2 * k] = blo(v); f[2 * k + 1] = bhi(v);
    }
#pragma unroll
    for (int e = 0; e < 34; e++) {
      const float* w = x_proj_w + e * DI + c2 * 16;
      float a = xdb[e];
#pragma unroll
      for (int i = 0; i < 16; i++) a = fmaf(f[i], w[i], a);
      xdb[e] = a;
    }
  }
  unsigned* row = &uS[tid * 33];
  row[0] = pack2(xdb[0], xdb[1]);
#pragma unroll
  for (int n = 0; n < 8; n++) row[4 + n]  = pack2(xdb[2 + 2 * n], xdb[3 + 2 * n]);
#pragma unroll
  for (int n = 0; n < 8; n++) row[12 + n] = pack2(xdb[18 + 2 * n], xdb[19 + 2 * n]);
  __syncthreads();
  unsigned* dst = xdbl + pos0 * XROW;
#pragma unroll
  for (int k = 0; k < XROW; k++) {
    int idx = tid + k * 256;
    int r = idx / XROW, c = idx - r * XROW;
    dst[idx] = uS[r * 33 + c];
  }
}

// A2[n] == (n+1)*A2[0] for this problem's A = arange(1..16); guarded fast path.
__device__ __forceinline__ bool ladder_check(const float* A_log, int d, float a0) {
  bool ok = true;
#pragma unroll
  for (int n = 1; n < DSN; n++) {
    float an = -__expf(A_log[d * DSN + n]) * 1.44269504088896f;
    ok = ok && (fabsf(an / a0 - (float)(n + 1)) < 1e-3f);
  }
  return ok;
}

// ---------------- K3: scan pass A — local states + chunk delta-sums ----------------
// (unchanged from round 4)
__global__ __launch_bounds__(256, 8) void k3_scanA(
    const unsigned* __restrict__ xdbl, const bf* __restrict__ u_ws,
    const float* __restrict__ A_log, const float* __restrict__ dt_proj_w,
    const float* __restrict__ dt_proj_b,
    __half* __restrict__ hloc, __half* __restrict__ ssum_ws) {
  int tid = threadIdx.x;
  int wid = __builtin_amdgcn_readfirstlane(blockIdx.x * 4 + (tid >> 6)); // linear (s,chunk)
  int s = wid >> 7, chunk = wid & (NC - 1);
  int d = tid & 63;
  float a0 = -__expf(A_log[d * DSN]) * 1.44269504088896f;
  bool ok = ladder_check(A_log, d, a0);
  float w0 = dt_proj_w[2 * d], w1 = dt_proj_w[2 * d + 1], bd = dt_proj_b[d];
  float h[DSN];
#pragma unroll
  for (int n = 0; n < DSN; n++) h[n] = 0.f;
  float ss = 0.f;
  size_t base = (size_t)s * LL + (size_t)chunk * CL;
  const unsigned short* up = (const unsigned short*)u_ws + base * DI + d;
  const unsigned* xrow = xdbl + base * XROW;
  if (ok) {
    for (int t = 0; t < CL; t++) {
      const unsigned* r = xrow + t * XROW;
      unsigned dtp = r[0];
      float x = fmaf(bhi(dtp), w1, fmaf(blo(dtp), w0, bd));
      float delta = softplus_fast(x);
      float uu = us2f(up[(size_t)t * DI]);
      float Bv[16];
      unpack8(((const uint4*)(r + 4))[0], Bv);
      unpack8(((const uint4*)(r + 4))[1], Bv + 8);
      float du = delta * uu;
      ss += delta;
      float E = EXP2F(delta * a0);
      float e = E;
#pragma unroll
      for (int n = 0; n < DSN; n++) {
        h[n] = fmaf(h[n], e, du * Bv[n]);
        e *= E;
      }
    }
  } else {
    float A2[DSN];
#pragma unroll
    for (int n = 0; n < DSN; n++)
      A2[n] = -__expf(A_log[d * DSN + n]) * 1.44269504088896f;
    for (int t = 0; t < CL; t++) {
      const unsigned* r = xrow + t * XROW;
      unsigned dtp = r[0];
      float x = fmaf(bhi(dtp), w1, fmaf(blo(dtp), w0, bd));
      float delta = softplus_fast(x);
      float uu = us2f(up[(size_t)t * DI]);
      float Bv[16];
      unpack8(((const uint4*)(r + 4))[0], Bv);
      unpack8(((const uint4*)(r + 4))[1], Bv + 8);
      float du = delta * uu;
      ss += delta;
#pragma unroll
      for (int n = 0; n < DSN; n++) {
        float e = EXP2F(delta * A2[n]);
        h[n] = fmaf(h[n], e, du * Bv[n]);
      }
    }
  }
  size_t ob = (size_t)wid * (DSN * DI) + d;
#pragma unroll
  for (int n = 0; n < DSN; n++) hloc[ob + n * DI] = __float2half(h[n]);
  ssum_ws[wid * DI + d] = __float2half(ss);
}

// ---------------- K4: cross-chunk combine ----------------
// (unchanged from round 4)
__global__ __launch_bounds__(1024) void k4_combine(
    const __half* __restrict__ ssum_ws, const float* __restrict__ A_log, __half* hloc_hin) {
  int s = blockIdx.x;
  int tid = threadIdx.x;
  int n = tid >> 6, d = tid & 63;
  float A2 = -__expf(A_log[d * DSN + n]) * 1.44269504088896f;
  float h = 0.f;
  for (int k = 0; k < NC; k++) {
    size_t idx = (size_t)(s * NC + k) * (DSN * DI) + n * DI + d;
    float ss = __half2float(ssum_ws[(s * NC + k) * DI + d]);
    float ap = EXP2F(A2 * ss);
    float hl = __half2float(hloc_hin[idx]);
    hloc_hin[idx] = __float2half(h);
    h = fmaf(h, ap, hl);
  }
}

// ---------------- K56: scan pass C (y2 -> LDS) + z-gate + out_proj + residual -> output (fp32) ----------------
// Round-6: round-4's proven padded y2S layout (33792 B, stride-33 — the round-5 XOR
// swizzle is reverted as the only never-run-on-HW code in the crashed round), keeping
// round-5's two scheduling changes:
//  * z-projection hoisted BEFORE the first barrier (scan-independent -> absorbs
//    scan-straggler variance instead of serializing after the barrier).
//  * balanced out_proj: phase A both waves compute partials for the OTHER wave's jj
//    half; phase B each wave finalizes + stores its own 16 rows (halves serial tail).
__global__ __launch_bounds__(512, 4) void k56_scan_final(
    const unsigned* __restrict__ xdbl, const bf* __restrict__ u_ws,
    const float* __restrict__ A_log, const float* __restrict__ dt_proj_w,
    const float* __restrict__ dt_proj_b, const float* __restrict__ Dw,
    const __half* __restrict__ hin, const bf* __restrict__ xn_ws,
    const float* __restrict__ in_proj_w, const float* __restrict__ out_proj_w,
    float* __restrict__ out) {
  __shared__ unsigned y2S[4 * 64 * 33];            // per-g: 64 rows(col) x 33 dw (d-pairs)
  int b = blockIdx.x >> 6;
  int cpair = blockIdx.x & 63;                     // 64 col-tiles of 64
  int l0b = cpair * 64;                            // block's first output column
  int tid = threadIdx.x;
  int w = __builtin_amdgcn_readfirstlane(tid >> 6); // 0..7
  int g = w >> 1, half = w & 1;
  int d = tid & 63;
  int chunk = cpair * 2 + half;                    // scalar
  int s_u = __builtin_amdgcn_readfirstlane(g * BB + b);
  float a0 = -__expf(A_log[d * DSN]) * 1.44269504088896f;
  bool ok = ladder_check(A_log, d, a0);
  float w0 = dt_proj_w[2 * d], w1 = dt_proj_w[2 * d + 1], bd = dt_proj_b[d];
  float Dd = Dw[d];
  float h[DSN];
  size_t hb = (size_t)(s_u * NC + chunk) * (DSN * DI) + d;
#pragma unroll
  for (int n = 0; n < DSN; n++) h[n] = __half2float(hin[hb + n * DI]);
  size_t base = (size_t)s_u * LL + (size_t)chunk * CL;
  const unsigned short* up = (const unsigned short*)u_ws + base * DI + d;
  const unsigned* xrow = xdbl + base * XROW;       // scalar base -> s_load rows
  unsigned short* yout = (unsigned short*)y2S + g * 4224 + (half * CL) * 66 + d;
  if (ok) {
    for (int t = 0; t < CL; t++) {
      const unsigned* r = xrow + t * XROW;
      unsigned dtp = r[0];
      float x = fmaf(bhi(dtp), w1, fmaf(blo(dtp), w0, bd));
      float delta = softplus_fast(x);
      float uu = us2f(up[(size_t)t * DI]);
      float Bv[16], Cv[16];
      unpack8(((const uint4*)(r + 4))[0], Bv);
      unpack8(((const uint4*)(r + 4))[1], Bv + 8);
      unpack8(((const uint4*)(r + 12))[0], Cv);
      unpack8(((const uint4*)(r + 12))[1], Cv + 8);
      float du = delta * uu;
      float y = 0.f;
      float E = EXP2F(delta * a0);
      float e = E;
#pragma unroll
      for (int n = 0; n < DSN; n++) {
        h[n] = fmaf(h[n], e, du * Bv[n]);
        y = fmaf(h[n], Cv[n], y);
        e *= E;
      }
      bf rv = f2bf(y + uu * Dd);
      yout[t * 66] = *(unsigned short*)&rv;
    }
  } else {
    float A2[DSN];
#pragma unroll
    for (int n = 0; n < DSN; n++)
      A2[n] = -__expf(A_log[d * DSN + n]) * 1.44269504088896f;
    for (int t = 0; t < CL; t++) {
      const unsigned* r = xrow + t * XROW;
      unsigned dtp = r[0];
      float x = fmaf(bhi(dtp), w1, fmaf(blo(dtp), w0, bd));
      float delta = softplus_fast(x);
      float uu = us2f(up[(size_t)t * DI]);
      float Bv[16], Cv[16];
      unpack8(((const uint4*)(r + 4))[0], Bv);
      unpack8(((const uint4*)(r + 4))[1], Bv + 8);
      unpack8(((const uint4*)(r + 12))[0], Cv);
      unpack8(((const uint4*)(r + 12))[1], Cv + 8);
      float du = delta * uu;
      float y = 0.f;
#pragma unroll
      for (int n = 0; n < DSN; n++) {
        float e = EXP2F(delta * A2[n]);
        h[n] = fmaf(h[n], e, du * Bv[n]);
        y = fmaf(h[n], Cv[n], y);
      }
      bf rv = f2bf(y + uu * Dd);
      yout[t * 66] = *(unsigned short*)&rv;
    }
  }
  // ---- z projection (scan-independent): BEFORE the barrier to hide straggler variance ----
  int p = half;
  int j = d;
  const unsigned short* xnp = (const unsigned short*)xn_ws
                            + ((size_t)(b * CC + g * DM)) * LL + l0b + j;
  float acc[32];                                   // this wave's dd = p*32 .. p*32+31
#pragma unroll
  for (int dd = 0; dd < 32; dd++) acc[dd] = 0.f;
#pragma unroll
  for (int c4 = 0; c4 < 4; c4++) {
    float xc[8];
#pragma unroll
    for (int r8 = 0; r8 < 8; r8++)
      xc[r8] = us2f(xnp[(size_t)(c4 * 8 + r8) * LL]);   // lanes j consecutive -> coalesced
#pragma unroll
    for (int dd = 0; dd < 32; dd++) {              // weights wave-uniform -> s_load
      const float* wz = in_proj_w + (DI + p * 32 + dd) * DM + c4 * 8;
      float a = acc[dd];
#pragma unroll
      for (int r8 = 0; r8 < 8; r8++) a = fmaf(xc[r8], wz[r8], a);
      acc[dd] = a;
    }
  }
  __syncthreads();                                 // scan writes complete
  // ---- gate: y3 = y2 * silu(z); own (g,j) row, this wave's dword cols p*16..p*16+15 ----
  const unsigned* yrow = y2S + g * 2112 + j * 33;  // banks (j+k)%32 -> conflict-free
#pragma unroll
  for (int kk = 0; kk < 16; kk++) {
    unsigned v = yrow[p * 16 + kk];
    float z0 = acc[2 * kk], z1 = acc[2 * kk + 1];
    acc[2 * kk]     = blo(v) * (z0 * sigmoidf_(z0));
    acc[2 * kk + 1] = bhi(v) * (z1 * sigmoidf_(z1));
  }
  __syncthreads();                                 // y2S fully consumed -> reuse as partials
  // ---- phase A: partials for the OTHER wave's jj half (both waves work) ----
  float* prow = (float*)y2S + g * 2112 + j * 33;   // stride-33 -> conflict-free
  int jjb = (1 - p) * 16;
#pragma unroll
  for (int jj = 0; jj < 16; jj++) {
    const float* wo = out_proj_w + (jjb + jj) * DI + p * 32;
    float a = 0.f;
#pragma unroll
    for (int dd = 0; dd < 32; dd++) a = fmaf(acc[dd], wo[dd], a);
    prow[jjb + jj] = a;
  }
  __syncthreads();
  // ---- phase B: finalize own half (partial + own dot + residual), store 16 rows/wave ----
  int jf = p * 16;
  float* ob = out + ((size_t)(b * CC + g * DM)) * LL + l0b + j;
#pragma unroll
  for (int jj = 0; jj < 16; jj++) {
    const float* wo = out_proj_w + (jf + jj) * DI + p * 32;
    float a = us2f(xnp[(size_t)(jf + jj) * LL]) + prow[jf + jj];
#pragma unroll
    for (int dd = 0; dd < 32; dd++) a = fmaf(acc[dd], wo[dd], a);
    ob[(size_t)(jf + jj) * LL] = a;                // coalesced 256B
  }
}

extern "C" void kernel_launch(void* const* d_in, const int* in_sizes, int n_in,
                              void* d_out, int out_size, void* d_ws, size_t ws_size,
                              hipStream_t stream) {
  const float* input     = (const float*)d_in[0];
  const float* ln_g      = (const float*)d_in[1];
  const float* ln_b      = (const float*)d_in[2];
  const float* in_proj_w = (const float*)d_in[3];
  const float* conv_w    = (const float*)d_in[4];
  const float* conv_b    = (const float*)d_in[5];
  const float* x_proj_w  = (const float*)d_in[6];
  const float* dt_proj_w = (const float*)d_in[7];
  const float* dt_proj_b = (const float*)d_in[8];
  const float* A_log     = (const float*)d_in[9];
  const float* Dw        = (const float*)d_in[10];
  const float* out_proj_w= (const float*)d_in[11];
  float* out = (float*)d_out;

  char* ws = (char*)d_ws;
  bf*       u_ws  = (bf*)(ws);                    // 32 MiB
  unsigned* xdbl  = (unsigned*)(ws + 33554432);   // 20 MiB
  bf*       xn_ws = (bf*)(ws + 54525952);         // 16 MiB
  __half*   hloc  = (__half*)(ws + 71303168);     // 16 MiB fp16 (NC=128; hin aliases after k4)
  __half*   ssum  = (__half*)(ws + 88080384);     // 1 MiB fp16 (total 89,128,960 B — known-good)
  (void)in_sizes; (void)n_in; (void)out_size; (void)ws_size;

  hipLaunchKernelGGL(k1_ln_conv, dim3(BB * NT), dim3(256), 0, stream,
                     input, ln_g, ln_b, in_proj_w, conv_w, conv_b, u_ws, xn_ws);
  hipLaunchKernelGGL(k2_xproj, dim3(1024), dim3(256), 0, stream,
                     u_ws, x_proj_w, xdbl);
  hipLaunchKernelGGL(k3_scanA, dim3(GG * NC / 4), dim3(256), 0, stream,
                     xdbl, u_ws, A_log, dt_proj_w, dt_proj_b, hloc, ssum);
  hipLaunchKernelGGL(k4_combine, dim3(GG), dim3(1024), 0, stream,
                     ssum, A_log, hloc);
  hipLaunchKernelGGL(k56_scan_final, dim3(BB * NC / 2), dim3(512), 0, stream,
                     xdbl, u_ws, A_log, dt_proj_w, dt_proj_b, Dw, hloc, xn_ws,
                     in_proj_w, out_proj_w, out);
}

// Round 7
// 408.789 us; speedup vs baseline: 1.0763x; 1.0763x over previous
//
#include <hip/hip_runtime.h>
#include <hip/hip_bf16.h>
#include <hip/hip_fp16.h>
#include <math.h>

typedef __hip_bfloat16 bf;

#define BB   16     // batch
#define CC   128    // channels
#define LL   4096   // H*W
#define DM   32     // d_model per chunk
#define DI   64     // d_inner
#define DSN  16     // d_state
#define GG   64     // 4 * BB sequences
#define NC   128    // scan chunks (CL=32)
#define CL   32     // LL / NC
#define TLV  61     // valid output columns per k1 tile (64 loaded, 3 head)
#define NT   68     // ceil(LL / TLV)
#define XS   133    // k1 xnT row stride in dwords (odd -> conflict-free)
#define YS   35     // k1 xiS row stride in dwords
#define XROW 20     // xdbl row stride in dwords (80 B: dw0=dt01, dw1-3 pad, dw4-11=B, dw12-19=C)

__device__ __forceinline__ float bf2f(bf x) { return __bfloat162float(x); }
__device__ __forceinline__ bf f2bf(float x) { return __float2bfloat16(x); }
__device__ __forceinline__ float blo(unsigned v) { return __uint_as_float(v << 16); }
__device__ __forceinline__ float bhi(unsigned v) { return __uint_as_float(v & 0xffff0000u); }
__device__ __forceinline__ float us2f(unsigned short v) { return __uint_as_float((unsigned)v << 16); }
__device__ __forceinline__ unsigned pack2(float a, float b) {
  bf ba = f2bf(a), bb = f2bf(b);
  unsigned short ua = *(unsigned short*)&ba, ub = *(unsigned short*)&bb;
  return (unsigned)ua | ((unsigned)ub << 16);
}

#if __has_builtin(__builtin_amdgcn_exp2f)
#define EXP2F(x) __builtin_amdgcn_exp2f(x)
#else
#define EXP2F(x) exp2f(x)
#endif

__device__ __forceinline__ float sigmoidf_(float x) { return 1.0f / (1.0f + __expf(-x)); }
// fast softplus: max(x,0) + ln2 * log2(1 + exp2(-|x|*log2e))
__device__ __forceinline__ float softplus_fast(float x) {
  float t = EXP2F(-fabsf(x) * 1.44269504088896f);
  return fmaxf(x, 0.0f) + 0.69314718056f * __log2f(1.0f + t);
}
__device__ __forceinline__ void unpack8(uint4 v, float* o) {
  o[0] = blo(v.x); o[1] = bhi(v.x); o[2] = blo(v.y); o[3] = bhi(v.y);
  o[4] = blo(v.z); o[5] = bhi(v.z); o[6] = blo(v.w); o[7] = bhi(v.w);
}

// ---------------- K1: layernorm + in_proj(xi) + causal conv + silu -> u (bf16), xn (bf16) ----------------
// (unchanged)
__global__ __launch_bounds__(256, 4) void k1_ln_conv(
    const float* __restrict__ input, const float* __restrict__ ln_g, const float* __restrict__ ln_b,
    const float* __restrict__ in_proj_w, const float* __restrict__ conv_w, const float* __restrict__ conv_b,
    bf* __restrict__ u_ws, bf* __restrict__ xn_ws) {
  __shared__ unsigned ldsbuf[8960];               // union: xnT fp32 64x133dw / xiS bf16 256x35dw
  __shared__ float mu_s[64], rs_s[64];
  float* xnT = (float*)ldsbuf;
  unsigned short* xiS = (unsigned short*)ldsbuf;
  int b = blockIdx.x / NT;
  int tile = blockIdx.x - b * NT;
  int l0 = tile * TLV;
  int tid = threadIdx.x;
  const float* inb = input + (size_t)b * CC * LL;
#pragma unroll
  for (int k = 0; k < 32; k++) {
    int i = tid + k * 256;
    int j = i & 63, c = i >> 6;
    int l = l0 - 3 + j;
    xnT[j * XS + c] = (l >= 0 && l < LL) ? inb[c * LL + l] : 0.0f;
  }
  __syncthreads();
  if (tid < 64) {
    float s = 0.f, s2 = 0.f;
    for (int c = 0; c < CC; c++) { float v = xnT[tid * XS + c]; s += v; s2 = fmaf(v, v, s2); }
    float mu = s * (1.0f / CC);
    float var = s2 * (1.0f / CC) - mu * mu;
    mu_s[tid] = mu;
    rs_s[tid] = rsqrtf(var + 1e-5f);
  }
  __syncthreads();
#pragma unroll
  for (int k = 0; k < 32; k++) {
    int i = tid + k * 256;
    int j = i & 63, c = i >> 6;
    xnT[j * XS + c] = (xnT[j * XS + c] - mu_s[j]) * rs_s[j] * ln_g[c] + ln_b[c];
  }
  __syncthreads();
  for (int i = tid; i < CC * TLV; i += 256) {
    int c = i / TLV, j2 = i - c * TLV;
    int l = l0 + j2;
    if (l < LL) xn_ws[((size_t)(b * CC + c)) * LL + l] = f2bf(xnT[(j2 + 3) * XS + c]);
  }
  int g = tid >> 6, j = tid & 63;
  float xr[32];
#pragma unroll
  for (int r = 0; r < 32; r++) xr[r] = xnT[j * XS + g * DM + r];
  bool zero_col = (l0 - 3 + j < 0);
  __syncthreads();
#pragma unroll
  for (int c2 = 0; c2 < 4; c2++) {
    float acc[16];
#pragma unroll
    for (int dd = 0; dd < 16; dd++) {
      const float* w = in_proj_w + (c2 * 16 + dd) * DM;
      float a = 0.f;
#pragma unroll
      for (int r = 0; r < 32; r++) a = fmaf(xr[r], w[r], a);
      acc[dd] = zero_col ? 0.f : a;
    }
    unsigned* xo = (unsigned*)&ldsbuf[(g * 64 + j) * YS + c2 * 8];
#pragma unroll
    for (int k = 0; k < 8; k++)
      xo[k] = pack2(acc[2 * k], acc[2 * k + 1]);
  }
  __syncthreads();
  int d = j;
  float cw0 = conv_w[d * 4 + 0], cw1 = conv_w[d * 4 + 1];
  float cw2 = conv_w[d * 4 + 2], cw3 = conv_w[d * 4 + 3];
  float cb = conv_b[d];
  bf* uo = u_ws + (size_t)(g * BB + b) * LL * DI + d;
  float x3 = 0.f, x2 = 0.f, x1 = 0.f, x0 = 0.f;
  for (int jj = 0; jj < 64; jj++) {
    float xi = us2f(xiS[(g * 64 + jj) * (2 * YS) + d]);
    x3 = x2; x2 = x1; x1 = x0; x0 = xi;
    int l = l0 + jj - 3;
    if (jj >= 3 && l < LL) {
      float pre = x3 * cw0 + x2 * cw1 + x1 * cw2 + x0 * cw3 + cb;
      float uu = pre * sigmoidf_(pre);
      uo[(size_t)l * DI] = f2bf(uu);
    }
  }
}

// ---------------- K2: x_proj only -> xdbl rows (dt0,dt1,B,C packed bf16, 80 B/pos) ----------------
// (unchanged)
__global__ __launch_bounds__(256) void k2_xproj(
    const bf* __restrict__ u_ws, const float* __restrict__ x_proj_w,
    unsigned* __restrict__ xdbl) {
  __shared__ unsigned uS[256 * 33];
  int tid = threadIdx.x;
  size_t pos0 = (size_t)blockIdx.x * 256;
  const unsigned* src = (const unsigned*)u_ws + pos0 * 32;
#pragma unroll
  for (int k = 0; k < 32; k++) {
    int idx = tid + k * 256;
    uS[(idx >> 5) * 33 + (idx & 31)] = src[idx];
  }
  __syncthreads();
  float xdb[34];
#pragma unroll
  for (int e = 0; e < 34; e++) xdb[e] = 0.f;
#pragma unroll
  for (int c2 = 0; c2 < 4; c2++) {
    float f[16];
#pragma unroll
    for (int k = 0; k < 8; k++) {
      unsigned v = uS[tid * 33 + c2 * 8 + k];
      f[2 * k] = blo(v); f[2 * k + 1] = bhi(v);
    }
#pragma unroll
    for (int e = 0; e < 34; e++) {
      const float* w = x_proj_w + e * DI + c2 * 16;
      float a = xdb[e];
#pragma unroll
      for (int i = 0; i < 16; i++) a = fmaf(f[i], w[i], a);
      xdb[e] = a;
    }
  }
  unsigned* row = &uS[tid * 33];
  row[0] = pack2(xdb[0], xdb[1]);
#pragma unroll
  for (int n = 0; n < 8; n++) row[4 + n]  = pack2(xdb[2 + 2 * n], xdb[3 + 2 * n]);
#pragma unroll
  for (int n = 0; n < 8; n++) row[12 + n] = pack2(xdb[18 + 2 * n], xdb[19 + 2 * n]);
  __syncthreads();
  unsigned* dst = xdbl + pos0 * XROW;
#pragma unroll
  for (int k = 0; k < XROW; k++) {
    int idx = tid + k * 256;
    int r = idx / XROW, c = idx - r * XROW;
    dst[idx] = uS[r * 33 + c];
  }
}

// A2[n] == (n+1)*A2[0] for this problem's A = arange(1..16); guarded fast path.
__device__ __forceinline__ bool ladder_check(const float* A_log, int d, float a0) {
  bool ok = true;
#pragma unroll
  for (int n = 1; n < DSN; n++) {
    float an = -__expf(A_log[d * DSN + n]) * 1.44269504088896f;
    ok = ok && (fabsf(an / a0 - (float)(n + 1)) < 1e-3f);
  }
  return ok;
}

// ---------------- K3: scan pass A — local states + chunk delta-sums ----------------
// launch_bounds arg2 8 -> 4: empirically (X,8) clamps the VGPR budget to ~32
// (round-3: (512,8) gave VGPR=32 + massive scratch spill). (X,4) budgets ~64;
// actual VGPR (<64) still allows 8 waves/SIMD at runtime.
__global__ __launch_bounds__(256, 4) void k3_scanA(
    const unsigned* __restrict__ xdbl, const bf* __restrict__ u_ws,
    const float* __restrict__ A_log, const float* __restrict__ dt_proj_w,
    const float* __restrict__ dt_proj_b,
    __half* __restrict__ hloc, __half* __restrict__ ssum_ws) {
  int tid = threadIdx.x;
  int wid = __builtin_amdgcn_readfirstlane(blockIdx.x * 4 + (tid >> 6)); // linear (s,chunk)
  int s = wid >> 7, chunk = wid & (NC - 1);
  int d = tid & 63;
  float a0 = -__expf(A_log[d * DSN]) * 1.44269504088896f;
  bool ok = ladder_check(A_log, d, a0);
  float w0 = dt_proj_w[2 * d], w1 = dt_proj_w[2 * d + 1], bd = dt_proj_b[d];
  float h[DSN];
#pragma unroll
  for (int n = 0; n < DSN; n++) h[n] = 0.f;
  float ss = 0.f;
  size_t base = (size_t)s * LL + (size_t)chunk * CL;
  const unsigned short* up = (const unsigned short*)u_ws + base * DI + d;
  const unsigned* xrow = xdbl + base * XROW;
  if (ok) {
    for (int t = 0; t < CL; t++) {
      const unsigned* r = xrow + t * XROW;
      unsigned dtp = r[0];
      float x = fmaf(bhi(dtp), w1, fmaf(blo(dtp), w0, bd));
      float delta = softplus_fast(x);
      float uu = us2f(up[(size_t)t * DI]);
      float Bv[16];
      unpack8(((const uint4*)(r + 4))[0], Bv);
      unpack8(((const uint4*)(r + 4))[1], Bv + 8);
      float du = delta * uu;
      ss += delta;
      float E = EXP2F(delta * a0);
      float e = E;
#pragma unroll
      for (int n = 0; n < DSN; n++) {
        h[n] = fmaf(h[n], e, du * Bv[n]);
        e *= E;
      }
    }
  } else {
    float A2[DSN];
#pragma unroll
    for (int n = 0; n < DSN; n++)
      A2[n] = -__expf(A_log[d * DSN + n]) * 1.44269504088896f;
    for (int t = 0; t < CL; t++) {
      const unsigned* r = xrow + t * XROW;
      unsigned dtp = r[0];
      float x = fmaf(bhi(dtp), w1, fmaf(blo(dtp), w0, bd));
      float delta = softplus_fast(x);
      float uu = us2f(up[(size_t)t * DI]);
      float Bv[16];
      unpack8(((const uint4*)(r + 4))[0], Bv);
      unpack8(((const uint4*)(r + 4))[1], Bv + 8);
      float du = delta * uu;
      ss += delta;
#pragma unroll
      for (int n = 0; n < DSN; n++) {
        float e = EXP2F(delta * A2[n]);
        h[n] = fmaf(h[n], e, du * Bv[n]);
      }
    }
  }
  size_t ob = (size_t)wid * (DSN * DI) + d;
#pragma unroll
  for (int n = 0; n < DSN; n++) hloc[ob + n * DI] = __float2half(h[n]);
  ssum_ws[wid * DI + d] = __float2half(ss);
}

// ---------------- K4: cross-chunk combine ----------------
// (unchanged from round 4)
__global__ __launch_bounds__(1024) void k4_combine(
    const __half* __restrict__ ssum_ws, const float* __restrict__ A_log, __half* hloc_hin) {
  int s = blockIdx.x;
  int tid = threadIdx.x;
  int n = tid >> 6, d = tid & 63;
  float A2 = -__expf(A_log[d * DSN + n]) * 1.44269504088896f;
  float h = 0.f;
  for (int k = 0; k < NC; k++) {
    size_t idx = (size_t)(s * NC + k) * (DSN * DI) + n * DI + d;
    float ss = __half2float(ssum_ws[(s * NC + k) * DI + d]);
    float ap = EXP2F(A2 * ss);
    float hl = __half2float(hloc_hin[idx]);
    hloc_hin[idx] = __float2half(h);
    h = fmaf(h, ap, hl);
  }
}

// ---------------- K56: scan pass C (y2 -> LDS) + z-gate + out_proj + residual -> output (fp32) ----------------
// Round-7: the 4 g-groups never share data (y2S, gate, partial exchange are all per-g),
// so split the 512-thread block into 4 per-g blocks: 4096 blocks x 128 threads,
// LDS 8448 B. Finer granules pack up to 16 blocks/CU (vs 2 measured at 512/33KB) and
// barriers couple only 2 waves. Scan body + epilogue are the round-4 code verbatim
// (round-6's z-hoist is reverted: it blew acc[32] live range across the scan ->
// VGPR 64 + 37 MB scratch spill).
__global__ __launch_bounds__(128, 4) void k56_scan_final(
    const unsigned* __restrict__ xdbl, const bf* __restrict__ u_ws,
    const float* __restrict__ A_log, const float* __restrict__ dt_proj_w,
    const float* __restrict__ dt_proj_b, const float* __restrict__ Dw,
    const __half* __restrict__ hin, const bf* __restrict__ xn_ws,
    const float* __restrict__ in_proj_w, const float* __restrict__ out_proj_w,
    float* __restrict__ out) {
  __shared__ unsigned y2S[64 * 33];                // 8448 B: 64 rows(col) x 33 dw (d-pairs)
  int bid = blockIdx.x;
  int g = bid & 3;
  int cpair = (bid >> 2) & 63;                     // 64 col-tiles of 64
  int b = bid >> 8;
  int l0b = cpair * 64;                            // block's first output column
  int tid = threadIdx.x;
  int half = __builtin_amdgcn_readfirstlane(tid >> 6); // 0..1
  int d = tid & 63;
  int chunk = cpair * 2 + half;                    // scalar
  int s_u = __builtin_amdgcn_readfirstlane(g * BB + b);
  float a0 = -__expf(A_log[d * DSN]) * 1.44269504088896f;
  bool ok = ladder_check(A_log, d, a0);
  float w0 = dt_proj_w[2 * d], w1 = dt_proj_w[2 * d + 1], bd = dt_proj_b[d];
  float Dd = Dw[d];
  float h[DSN];
  size_t hb = (size_t)(s_u * NC + chunk) * (DSN * DI) + d;
#pragma unroll
  for (int n = 0; n < DSN; n++) h[n] = __half2float(hin[hb + n * DI]);
  size_t base = (size_t)s_u * LL + (size_t)chunk * CL;
  const unsigned short* up = (const unsigned short*)u_ws + base * DI + d;
  const unsigned* xrow = xdbl + base * XROW;       // scalar base -> s_load rows
  unsigned short* yout = (unsigned short*)y2S + (half * CL) * 66 + d;
  if (ok) {
    for (int t = 0; t < CL; t++) {
      const unsigned* r = xrow + t * XROW;
      unsigned dtp = r[0];
      float x = fmaf(bhi(dtp), w1, fmaf(blo(dtp), w0, bd));
      float delta = softplus_fast(x);
      float uu = us2f(up[(size_t)t * DI]);
      float Bv[16], Cv[16];
      unpack8(((const uint4*)(r + 4))[0], Bv);
      unpack8(((const uint4*)(r + 4))[1], Bv + 8);
      unpack8(((const uint4*)(r + 12))[0], Cv);
      unpack8(((const uint4*)(r + 12))[1], Cv + 8);
      float du = delta * uu;
      float y = 0.f;
      float E = EXP2F(delta * a0);
      float e = E;
#pragma unroll
      for (int n = 0; n < DSN; n++) {
        h[n] = fmaf(h[n], e, du * Bv[n]);
        y = fmaf(h[n], Cv[n], y);
        e *= E;
      }
      bf rv = f2bf(y + uu * Dd);
      yout[t * 66] = *(unsigned short*)&rv;
    }
  } else {
    float A2[DSN];
#pragma unroll
    for (int n = 0; n < DSN; n++)
      A2[n] = -__expf(A_log[d * DSN + n]) * 1.44269504088896f;
    for (int t = 0; t < CL; t++) {
      const unsigned* r = xrow + t * XROW;
      unsigned dtp = r[0];
      float x = fmaf(bhi(dtp), w1, fmaf(blo(dtp), w0, bd));
      float delta = softplus_fast(x);
      float uu = us2f(up[(size_t)t * DI]);
      float Bv[16], Cv[16];
      unpack8(((const uint4*)(r + 4))[0], Bv);
      unpack8(((const uint4*)(r + 4))[1], Bv + 8);
      unpack8(((const uint4*)(r + 12))[0], Cv);
      unpack8(((const uint4*)(r + 12))[1], Cv + 8);
      float du = delta * uu;
      float y = 0.f;
#pragma unroll
      for (int n = 0; n < DSN; n++) {
        float e = EXP2F(delta * A2[n]);
        h[n] = fmaf(h[n], e, du * Bv[n]);
        y = fmaf(h[n], Cv[n], y);
      }
      bf rv = f2bf(y + uu * Dd);
      yout[t * 66] = *(unsigned short*)&rv;
    }
  }
  __syncthreads();
  // ---- gate + out_proj + residual (round-4 epilogue, g-offsets removed) ----
  int p = half;
  int j = d;
  const unsigned short* xnp = (const unsigned short*)xn_ws
                            + ((size_t)(b * CC + g * DM)) * LL + l0b + j;
  float acc[32];                                   // this wave's dd = p*32 .. p*32+31
#pragma unroll
  for (int dd = 0; dd < 32; dd++) acc[dd] = 0.f;
#pragma unroll
  for (int c4 = 0; c4 < 4; c4++) {                 // z projection (shared xc, split dd)
    float xc[8];
#pragma unroll
    for (int r8 = 0; r8 < 8; r8++)
      xc[r8] = us2f(xnp[(size_t)(c4 * 8 + r8) * LL]);   // lanes j consecutive -> coalesced
#pragma unroll
    for (int dd = 0; dd < 32; dd++) {              // weights wave-uniform -> s_load
      const float* wz = in_proj_w + (DI + p * 32 + dd) * DM + c4 * 8;
      float a = acc[dd];
#pragma unroll
      for (int r8 = 0; r8 < 8; r8++) a = fmaf(xc[r8], wz[r8], a);
      acc[dd] = a;
    }
  }
  const unsigned* yrow = y2S + j * 33;             // banks (j+k)%32 -> conflict-free
#pragma unroll
  for (int kk = 0; kk < 16; kk++) {                // gate: y3 = y2 * silu(z), this wave's pairs
    unsigned v = yrow[p * 16 + kk];
    float z0 = acc[2 * kk], z1 = acc[2 * kk + 1];
    acc[2 * kk]     = blo(v) * (z0 * sigmoidf_(z0));
    acc[2 * kk + 1] = bhi(v) * (z1 * sigmoidf_(z1));
  }
  __syncthreads();                                 // y2S fully consumed -> reuse as partials
  float* part = (float*)y2S + j * 33;              // 32 floats per j, stride-33
  if (p == 1) {
#pragma unroll
    for (int jj = 0; jj < DM; jj++) {
      const float* wo = out_proj_w + jj * DI + 32;
      float a = 0.f;
#pragma unroll
      for (int dd = 0; dd < 32; dd++) a = fmaf(acc[dd], wo[dd], a);
      part[jj] = a;
    }
  }
  __syncthreads();
  if (p == 0) {
    float* ob = out + ((size_t)(b * CC + g * DM)) * LL + l0b + j;
    for (int jj = 0; jj < DM; jj++) {              // out_proj + partial + residual
      const float* wo = out_proj_w + jj * DI;
      float a = us2f(xnp[(size_t)jj * LL]) + part[jj];
#pragma unroll
      for (int dd = 0; dd < 32; dd++) a = fmaf(acc[dd], wo[dd], a);
      ob[(size_t)jj * LL] = a;                     // coalesced 256B
    }
  }
}

extern "C" void kernel_launch(void* const* d_in, const int* in_sizes, int n_in,
                              void* d_out, int out_size, void* d_ws, size_t ws_size,
                              hipStream_t stream) {
  const float* input     = (const float*)d_in[0];
  const float* ln_g      = (const float*)d_in[1];
  const float* ln_b      = (const float*)d_in[2];
  const float* in_proj_w = (const float*)d_in[3];
  const float* conv_w    = (const float*)d_in[4];
  const float* conv_b    = (const float*)d_in[5];
  const float* x_proj_w  = (const float*)d_in[6];
  const float* dt_proj_w = (const float*)d_in[7];
  const float* dt_proj_b = (const float*)d_in[8];
  const float* A_log     = (const float*)d_in[9];
  const float* Dw        = (const float*)d_in[10];
  const float* out_proj_w= (const float*)d_in[11];
  float* out = (float*)d_out;

  char* ws = (char*)d_ws;
  bf*       u_ws  = (bf*)(ws);                    // 32 MiB
  unsigned* xdbl  = (unsigned*)(ws + 33554432);   // 20 MiB
  bf*       xn_ws = (bf*)(ws + 54525952);         // 16 MiB
  __half*   hloc  = (__half*)(ws + 71303168);     // 16 MiB fp16 (NC=128; hin aliases after k4)
  __half*   ssum  = (__half*)(ws + 88080384);     // 1 MiB fp16 (total 89,128,960 B — known-good)
  (void)in_sizes; (void)n_in; (void)out_size; (void)ws_size;

  hipLaunchKernelGGL(k1_ln_conv, dim3(BB * NT), dim3(256), 0, stream,
                     input, ln_g, ln_b, in_proj_w, conv_w, conv_b, u_ws, xn_ws);
  hipLaunchKernelGGL(k2_xproj, dim3(1024), dim3(256), 0, stream,
                     u_ws, x_proj_w, xdbl);
  hipLaunchKernelGGL(k3_scanA, dim3(GG * NC / 4), dim3(256), 0, stream,
                     xdbl, u_ws, A_log, dt_proj_w, dt_proj_b, hloc, ssum);
  hipLaunchKernelGGL(k4_combine, dim3(GG), dim3(1024), 0, stream,
                     ssum, A_log, hloc);
  hipLaunchKernelGGL(k56_scan_final, dim3(BB * NC * 2), dim3(128), 0, stream,
                     xdbl, u_ws, A_log, dt_proj_w, dt_proj_b, Dw, hloc, xn_ws,
                     in_proj_w, out_proj_w, out);
}

// Round 8
// 364.554 us; speedup vs baseline: 1.2069x; 1.1213x over previous
//
#include <hip/hip_runtime.h>
#include <hip/hip_bf16.h>
#include <hip/hip_fp16.h>
#include <math.h>

typedef __hip_bfloat16 bf;

#define BB   16     // batch
#define CC   128    // channels
#define LL   4096   // H*W
#define DM   32     // d_model per chunk
#define DI   64     // d_inner
#define DSN  16     // d_state
#define GG   64     // 4 * BB sequences
#define NC   128    // scan chunks (CL=32)
#define CL   32     // LL / NC
#define TLV  61     // valid output columns per k1 tile (64 loaded, 3 head)
#define NT   68     // ceil(LL / TLV)
#define XS   133    // k1 xnT row stride in dwords (odd -> conflict-free)
#define YS   35     // k1 xiS row stride in dwords
#define XROW 20     // xdbl row stride in dwords (80 B: dw0=dt01, dw1-3 pad, dw4-11=B, dw12-19=C)

__device__ __forceinline__ float bf2f(bf x) { return __bfloat162float(x); }
__device__ __forceinline__ bf f2bf(float x) { return __float2bfloat16(x); }
__device__ __forceinline__ float blo(unsigned v) { return __uint_as_float(v << 16); }
__device__ __forceinline__ float bhi(unsigned v) { return __uint_as_float(v & 0xffff0000u); }
__device__ __forceinline__ float us2f(unsigned short v) { return __uint_as_float((unsigned)v << 16); }
__device__ __forceinline__ unsigned pack2(float a, float b) {
  bf ba = f2bf(a), bb = f2bf(b);
  unsigned short ua = *(unsigned short*)&ba, ub = *(unsigned short*)&bb;
  return (unsigned)ua | ((unsigned)ub << 16);
}

#if __has_builtin(__builtin_amdgcn_exp2f)
#define EXP2F(x) __builtin_amdgcn_exp2f(x)
#else
#define EXP2F(x) exp2f(x)
#endif

__device__ __forceinline__ float sigmoidf_(float x) { return 1.0f / (1.0f + __expf(-x)); }
// fast softplus: max(x,0) + ln2 * log2(1 + exp2(-|x|*log2e))
__device__ __forceinline__ float softplus_fast(float x) {
  float t = EXP2F(-fabsf(x) * 1.44269504088896f);
  return fmaxf(x, 0.0f) + 0.69314718056f * __log2f(1.0f + t);
}
__device__ __forceinline__ void unpack8(uint4 v, float* o) {
  o[0] = blo(v.x); o[1] = bhi(v.x); o[2] = blo(v.y); o[3] = bhi(v.y);
  o[4] = blo(v.z); o[5] = bhi(v.z); o[6] = blo(v.w); o[7] = bhi(v.w);
}

// ---------------- K1: layernorm + in_proj(xi) + causal conv + silu -> u (bf16), xn (bf16) ----------------
// (unchanged)
__global__ __launch_bounds__(256, 4) void k1_ln_conv(
    const float* __restrict__ input, const float* __restrict__ ln_g, const float* __restrict__ ln_b,
    const float* __restrict__ in_proj_w, const float* __restrict__ conv_w, const float* __restrict__ conv_b,
    bf* __restrict__ u_ws, bf* __restrict__ xn_ws) {
  __shared__ unsigned ldsbuf[8960];               // union: xnT fp32 64x133dw / xiS bf16 256x35dw
  __shared__ float mu_s[64], rs_s[64];
  float* xnT = (float*)ldsbuf;
  unsigned short* xiS = (unsigned short*)ldsbuf;
  int b = blockIdx.x / NT;
  int tile = blockIdx.x - b * NT;
  int l0 = tile * TLV;
  int tid = threadIdx.x;
  const float* inb = input + (size_t)b * CC * LL;
#pragma unroll
  for (int k = 0; k < 32; k++) {
    int i = tid + k * 256;
    int j = i & 63, c = i >> 6;
    int l = l0 - 3 + j;
    xnT[j * XS + c] = (l >= 0 && l < LL) ? inb[c * LL + l] : 0.0f;
  }
  __syncthreads();
  if (tid < 64) {
    float s = 0.f, s2 = 0.f;
    for (int c = 0; c < CC; c++) { float v = xnT[tid * XS + c]; s += v; s2 = fmaf(v, v, s2); }
    float mu = s * (1.0f / CC);
    float var = s2 * (1.0f / CC) - mu * mu;
    mu_s[tid] = mu;
    rs_s[tid] = rsqrtf(var + 1e-5f);
  }
  __syncthreads();
#pragma unroll
  for (int k = 0; k < 32; k++) {
    int i = tid + k * 256;
    int j = i & 63, c = i >> 6;
    xnT[j * XS + c] = (xnT[j * XS + c] - mu_s[j]) * rs_s[j] * ln_g[c] + ln_b[c];
  }
  __syncthreads();
  for (int i = tid; i < CC * TLV; i += 256) {
    int c = i / TLV, j2 = i - c * TLV;
    int l = l0 + j2;
    if (l < LL) xn_ws[((size_t)(b * CC + c)) * LL + l] = f2bf(xnT[(j2 + 3) * XS + c]);
  }
  int g = tid >> 6, j = tid & 63;
  float xr[32];
#pragma unroll
  for (int r = 0; r < 32; r++) xr[r] = xnT[j * XS + g * DM + r];
  bool zero_col = (l0 - 3 + j < 0);
  __syncthreads();
#pragma unroll
  for (int c2 = 0; c2 < 4; c2++) {
    float acc[16];
#pragma unroll
    for (int dd = 0; dd < 16; dd++) {
      const float* w = in_proj_w + (c2 * 16 + dd) * DM;
      float a = 0.f;
#pragma unroll
      for (int r = 0; r < 32; r++) a = fmaf(xr[r], w[r], a);
      acc[dd] = zero_col ? 0.f : a;
    }
    unsigned* xo = (unsigned*)&ldsbuf[(g * 64 + j) * YS + c2 * 8];
#pragma unroll
    for (int k = 0; k < 8; k++)
      xo[k] = pack2(acc[2 * k], acc[2 * k + 1]);
  }
  __syncthreads();
  int d = j;
  float cw0 = conv_w[d * 4 + 0], cw1 = conv_w[d * 4 + 1];
  float cw2 = conv_w[d * 4 + 2], cw3 = conv_w[d * 4 + 3];
  float cb = conv_b[d];
  bf* uo = u_ws + (size_t)(g * BB + b) * LL * DI + d;
  float x3 = 0.f, x2 = 0.f, x1 = 0.f, x0 = 0.f;
  for (int jj = 0; jj < 64; jj++) {
    float xi = us2f(xiS[(g * 64 + jj) * (2 * YS) + d]);
    x3 = x2; x2 = x1; x1 = x0; x0 = xi;
    int l = l0 + jj - 3;
    if (jj >= 3 && l < LL) {
      float pre = x3 * cw0 + x2 * cw1 + x1 * cw2 + x0 * cw3 + cb;
      float uu = pre * sigmoidf_(pre);
      uo[(size_t)l * DI] = f2bf(uu);
    }
  }
}

// ---------------- K2: x_proj only -> xdbl rows (dt0,dt1,B,C packed bf16, 80 B/pos) ----------------
// (unchanged)
__global__ __launch_bounds__(256) void k2_xproj(
    const bf* __restrict__ u_ws, const float* __restrict__ x_proj_w,
    unsigned* __restrict__ xdbl) {
  __shared__ unsigned uS[256 * 33];
  int tid = threadIdx.x;
  size_t pos0 = (size_t)blockIdx.x * 256;
  const unsigned* src = (const unsigned*)u_ws + pos0 * 32;
#pragma unroll
  for (int k = 0; k < 32; k++) {
    int idx = tid + k * 256;
    uS[(idx >> 5) * 33 + (idx & 31)] = src[idx];
  }
  __syncthreads();
  float xdb[34];
#pragma unroll
  for (int e = 0; e < 34; e++) xdb[e] = 0.f;
#pragma unroll
  for (int c2 = 0; c2 < 4; c2++) {
    float f[16];
#pragma unroll
    for (int k = 0; k < 8; k++) {
      unsigned v = uS[tid * 33 + c2 * 8 + k];
      f[2 * k] = blo(v); f[2 * k + 1] = bhi(v);
    }
#pragma unroll
    for (int e = 0; e < 34; e++) {
      const float* w = x_proj_w + e * DI + c2 * 16;
      float a = xdb[e];
#pragma unroll
      for (int i = 0; i < 16; i++) a = fmaf(f[i], w[i], a);
      xdb[e] = a;
    }
  }
  unsigned* row = &uS[tid * 33];
  row[0] = pack2(xdb[0], xdb[1]);
#pragma unroll
  for (int n = 0; n < 8; n++) row[4 + n]  = pack2(xdb[2 + 2 * n], xdb[3 + 2 * n]);
#pragma unroll
  for (int n = 0; n < 8; n++) row[12 + n] = pack2(xdb[18 + 2 * n], xdb[19 + 2 * n]);
  __syncthreads();
  unsigned* dst = xdbl + pos0 * XROW;
#pragma unroll
  for (int k = 0; k < XROW; k++) {
    int idx = tid + k * 256;
    int r = idx / XROW, c = idx - r * XROW;
    dst[idx] = uS[r * 33 + c];
  }
}

// A2[n] == (n+1)*A2[0] for this problem's A = arange(1..16); guarded fast path.
__device__ __forceinline__ bool ladder_check(const float* A_log, int d, float a0) {
  bool ok = true;
#pragma unroll
  for (int n = 1; n < DSN; n++) {
    float an = -__expf(A_log[d * DSN + n]) * 1.44269504088896f;
    ok = ok && (fabsf(an / a0 - (float)(n + 1)) < 1e-3f);
  }
  return ok;
}

// ---------------- K3: scan pass A — local states + chunk delta-sums ----------------
// (byte-identical to round 4: (256,8) confirmed better than (256,4) by round-7 A/B)
__global__ __launch_bounds__(256, 8) void k3_scanA(
    const unsigned* __restrict__ xdbl, const bf* __restrict__ u_ws,
    const float* __restrict__ A_log, const float* __restrict__ dt_proj_w,
    const float* __restrict__ dt_proj_b,
    __half* __restrict__ hloc, __half* __restrict__ ssum_ws) {
  int tid = threadIdx.x;
  int wid = __builtin_amdgcn_readfirstlane(blockIdx.x * 4 + (tid >> 6)); // linear (s,chunk)
  int s = wid >> 7, chunk = wid & (NC - 1);
  int d = tid & 63;
  float a0 = -__expf(A_log[d * DSN]) * 1.44269504088896f;
  bool ok = ladder_check(A_log, d, a0);
  float w0 = dt_proj_w[2 * d], w1 = dt_proj_w[2 * d + 1], bd = dt_proj_b[d];
  float h[DSN];
#pragma unroll
  for (int n = 0; n < DSN; n++) h[n] = 0.f;
  float ss = 0.f;
  size_t base = (size_t)s * LL + (size_t)chunk * CL;
  const unsigned short* up = (const unsigned short*)u_ws + base * DI + d;
  const unsigned* xrow = xdbl + base * XROW;
  if (ok) {
    for (int t = 0; t < CL; t++) {
      const unsigned* r = xrow + t * XROW;
      unsigned dtp = r[0];
      float x = fmaf(bhi(dtp), w1, fmaf(blo(dtp), w0, bd));
      float delta = softplus_fast(x);
      float uu = us2f(up[(size_t)t * DI]);
      float Bv[16];
      unpack8(((const uint4*)(r + 4))[0], Bv);
      unpack8(((const uint4*)(r + 4))[1], Bv + 8);
      float du = delta * uu;
      ss += delta;
      float E = EXP2F(delta * a0);
      float e = E;
#pragma unroll
      for (int n = 0; n < DSN; n++) {
        h[n] = fmaf(h[n], e, du * Bv[n]);
        e *= E;
      }
    }
  } else {
    float A2[DSN];
#pragma unroll
    for (int n = 0; n < DSN; n++)
      A2[n] = -__expf(A_log[d * DSN + n]) * 1.44269504088896f;
    for (int t = 0; t < CL; t++) {
      const unsigned* r = xrow + t * XROW;
      unsigned dtp = r[0];
      float x = fmaf(bhi(dtp), w1, fmaf(blo(dtp), w0, bd));
      float delta = softplus_fast(x);
      float uu = us2f(up[(size_t)t * DI]);
      float Bv[16];
      unpack8(((const uint4*)(r + 4))[0], Bv);
      unpack8(((const uint4*)(r + 4))[1], Bv + 8);
      float du = delta * uu;
      ss += delta;
#pragma unroll
      for (int n = 0; n < DSN; n++) {
        float e = EXP2F(delta * A2[n]);
        h[n] = fmaf(h[n], e, du * Bv[n]);
      }
    }
  }
  size_t ob = (size_t)wid * (DSN * DI) + d;
#pragma unroll
  for (int n = 0; n < DSN; n++) hloc[ob + n * DI] = __float2half(h[n]);
  ssum_ws[wid * DI + d] = __float2half(ss);
}

// ---------------- K4: cross-chunk combine ----------------
// (unchanged from round 4)
__global__ __launch_bounds__(1024) void k4_combine(
    const __half* __restrict__ ssum_ws, const float* __restrict__ A_log, __half* hloc_hin) {
  int s = blockIdx.x;
  int tid = threadIdx.x;
  int n = tid >> 6, d = tid & 63;
  float A2 = -__expf(A_log[d * DSN + n]) * 1.44269504088896f;
  float h = 0.f;
  for (int k = 0; k < NC; k++) {
    size_t idx = (size_t)(s * NC + k) * (DSN * DI) + n * DI + d;
    float ss = __half2float(ssum_ws[(s * NC + k) * DI + d]);
    float ap = EXP2F(A2 * ss);
    float hl = __half2float(hloc_hin[idx]);
    hloc_hin[idx] = __float2half(h);
    h = fmaf(h, ap, hl);
  }
}

// ---------------- K56: scan pass C (y2 -> LDS) + z-gate + out_proj + residual -> output (fp32) ----------------
// Round-8 (round-4 512-thread structure + two changes):
//  * xdbl LDS staging: each wave one-shot coalesced-loads its chunk's 32 rows (2560 B)
//    into xdS, then reads per-step via ds_read (wave-uniform -> broadcast, no K$/L2 miss
//    per step). Replaces the per-step 17-dword s_load whose ~200-cyc L2 miss was the
//    ~46% VALU-idle (round-4 PMC). Unpack moves SALU->VALU (+~32 ops/step) — net win
//    iff the stall was the s_load chain.
//  * balanced out_proj (round-6's correct code): phase A both waves compute the OTHER
//    half's partials; phase B both finalize own 16 rows. z-proj stays AFTER the barrier
//    (round-6's z-hoist caused the acc-across-scan spill; not reinstated).
__global__ __launch_bounds__(512, 4) void k56_scan_final(
    const unsigned* __restrict__ xdbl, const bf* __restrict__ u_ws,
    const float* __restrict__ A_log, const float* __restrict__ dt_proj_w,
    const float* __restrict__ dt_proj_b, const float* __restrict__ Dw,
    const __half* __restrict__ hin, const bf* __restrict__ xn_ws,
    const float* __restrict__ in_proj_w, const float* __restrict__ out_proj_w,
    float* __restrict__ out) {
  __shared__ unsigned y2S[4 * 64 * 33];            // 33792 B: per-g 64 rows x 33 dw
  __shared__ unsigned xdS[8 * 640];                // 20480 B: per-wave 32 rows x 20 dw
  int b = blockIdx.x >> 6;
  int cpair = blockIdx.x & 63;                     // 64 col-tiles of 64
  int l0b = cpair * 64;                            // block's first output column
  int tid = threadIdx.x;
  int w = __builtin_amdgcn_readfirstlane(tid >> 6); // 0..7
  int g = w >> 1, half = w & 1;
  int d = tid & 63;
  int chunk = cpair * 2 + half;                    // scalar
  int s_u = __builtin_amdgcn_readfirstlane(g * BB + b);
  float a0 = -__expf(A_log[d * DSN]) * 1.44269504088896f;
  bool ok = ladder_check(A_log, d, a0);
  float w0 = dt_proj_w[2 * d], w1 = dt_proj_w[2 * d + 1], bd = dt_proj_b[d];
  float Dd = Dw[d];
  float h[DSN];
  size_t hb = (size_t)(s_u * NC + chunk) * (DSN * DI) + d;
#pragma unroll
  for (int n = 0; n < DSN; n++) h[n] = __half2float(hin[hb + n * DI]);
  size_t base = (size_t)s_u * LL + (size_t)chunk * CL;
  const unsigned short* up = (const unsigned short*)u_ws + base * DI + d;
  const unsigned* xrow = xdbl + base * XROW;
  // ---- one-shot coalesced stage of this wave's 32 xdbl rows into LDS ----
  int w640 = w * 640;
#pragma unroll
  for (int k = 0; k < 10; k++)
    xdS[w640 + k * 64 + d] = xrow[k * 64 + d];     // 10 x 256B coalesced; wave-private
  unsigned short* yout = (unsigned short*)y2S + g * 4224 + (half * CL) * 66 + d;
  if (ok) {
    for (int t = 0; t < CL; t++) {
      const unsigned* r = &xdS[w640 + t * XROW];   // ds_read, wave-uniform -> broadcast
      unsigned dtp = r[0];
      float x = fmaf(bhi(dtp), w1, fmaf(blo(dtp), w0, bd));
      float delta = softplus_fast(x);
      float uu = us2f(up[(size_t)t * DI]);
      float Bv[16], Cv[16];
      unpack8(((const uint4*)(r + 4))[0], Bv);
      unpack8(((const uint4*)(r + 4))[1], Bv + 8);
      unpack8(((const uint4*)(r + 12))[0], Cv);
      unpack8(((const uint4*)(r + 12))[1], Cv + 8);
      float du = delta * uu;
      float y = 0.f;
      float E = EXP2F(delta * a0);
      float e = E;
#pragma unroll
      for (int n = 0; n < DSN; n++) {
        h[n] = fmaf(h[n], e, du * Bv[n]);
        y = fmaf(h[n], Cv[n], y);
        e *= E;
      }
      bf rv = f2bf(y + uu * Dd);
      yout[t * 66] = *(unsigned short*)&rv;
    }
  } else {
    float A2[DSN];
#pragma unroll
    for (int n = 0; n < DSN; n++)
      A2[n] = -__expf(A_log[d * DSN + n]) * 1.44269504088896f;
    for (int t = 0; t < CL; t++) {
      const unsigned* r = &xdS[w640 + t * XROW];
      unsigned dtp = r[0];
      float x = fmaf(bhi(dtp), w1, fmaf(blo(dtp), w0, bd));
      float delta = softplus_fast(x);
      float uu = us2f(up[(size_t)t * DI]);
      float Bv[16], Cv[16];
      unpack8(((const uint4*)(r + 4))[0], Bv);
      unpack8(((const uint4*)(r + 4))[1], Bv + 8);
      unpack8(((const uint4*)(r + 12))[0], Cv);
      unpack8(((const uint4*)(r + 12))[1], Cv + 8);
      float du = delta * uu;
      float y = 0.f;
#pragma unroll
      for (int n = 0; n < DSN; n++) {
        float e = EXP2F(delta * A2[n]);
        h[n] = fmaf(h[n], e, du * Bv[n]);
        y = fmaf(h[n], Cv[n], y);
      }
      bf rv = f2bf(y + uu * Dd);
      yout[t * 66] = *(unsigned short*)&rv;
    }
  }
  __syncthreads();
  // ---- z projection (after barrier; acc never lives across the scan) ----
  int p = half;
  int j = d;
  const unsigned short* xnp = (const unsigned short*)xn_ws
                            + ((size_t)(b * CC + g * DM)) * LL + l0b + j;
  float acc[32];                                   // this wave's dd = p*32 .. p*32+31
#pragma unroll
  for (int dd = 0; dd < 32; dd++) acc[dd] = 0.f;
#pragma unroll
  for (int c4 = 0; c4 < 4; c4++) {
    float xc[8];
#pragma unroll
    for (int r8 = 0; r8 < 8; r8++)
      xc[r8] = us2f(xnp[(size_t)(c4 * 8 + r8) * LL]);   // lanes j consecutive -> coalesced
#pragma unroll
    for (int dd = 0; dd < 32; dd++) {              // weights wave-uniform -> s_load
      const float* wz = in_proj_w + (DI + p * 32 + dd) * DM + c4 * 8;
      float a = acc[dd];
#pragma unroll
      for (int r8 = 0; r8 < 8; r8++) a = fmaf(xc[r8], wz[r8], a);
      acc[dd] = a;
    }
  }
  // ---- gate: y3 = y2 * silu(z); own (g,j) row, this wave's dword cols p*16..p*16+15 ----
  const unsigned* yrow = y2S + g * 2112 + j * 33;  // banks (j+k)%32 -> conflict-free
#pragma unroll
  for (int kk = 0; kk < 16; kk++) {
    unsigned v = yrow[p * 16 + kk];
    float z0 = acc[2 * kk], z1 = acc[2 * kk + 1];
    acc[2 * kk]     = blo(v) * (z0 * sigmoidf_(z0));
    acc[2 * kk + 1] = bhi(v) * (z1 * sigmoidf_(z1));
  }
  __syncthreads();                                 // y2S fully consumed -> reuse as partials
  // ---- phase A: partials for the OTHER wave's jj half (both waves work) ----
  float* prow = (float*)y2S + g * 2112 + j * 33;   // stride-33 -> conflict-free
  int jjb = (1 - p) * 16;
#pragma unroll
  for (int jj = 0; jj < 16; jj++) {
    const float* wo = out_proj_w + (jjb + jj) * DI + p * 32;
    float a = 0.f;
#pragma unroll
    for (int dd = 0; dd < 32; dd++) a = fmaf(acc[dd], wo[dd], a);
    prow[jjb + jj] = a;
  }
  __syncthreads();
  // ---- phase B: finalize own half (partial + own dot + residual), store 16 rows/wave ----
  int jf = p * 16;
  float* ob = out + ((size_t)(b * CC + g * DM)) * LL + l0b + j;
#pragma unroll
  for (int jj = 0; jj < 16; jj++) {
    const float* wo = out_proj_w + (jf + jj) * DI + p * 32;
    float a = us2f(xnp[(size_t)(jf + jj) * LL]) + prow[jf + jj];
#pragma unroll
    for (int dd = 0; dd < 32; dd++) a = fmaf(acc[dd], wo[dd], a);
    ob[(size_t)(jf + jj) * LL] = a;                // coalesced 256B
  }
}

extern "C" void kernel_launch(void* const* d_in, const int* in_sizes, int n_in,
                              void* d_out, int out_size, void* d_ws, size_t ws_size,
                              hipStream_t stream) {
  const float* input     = (const float*)d_in[0];
  const float* ln_g      = (const float*)d_in[1];
  const float* ln_b      = (const float*)d_in[2];
  const float* in_proj_w = (const float*)d_in[3];
  const float* conv_w    = (const float*)d_in[4];
  const float* conv_b    = (const float*)d_in[5];
  const float* x_proj_w  = (const float*)d_in[6];
  const float* dt_proj_w = (const float*)d_in[7];
  const float* dt_proj_b = (const float*)d_in[8];
  const float* A_log     = (const float*)d_in[9];
  const float* Dw        = (const float*)d_in[10];
  const float* out_proj_w= (const float*)d_in[11];
  float* out = (float*)d_out;

  char* ws = (char*)d_ws;
  bf*       u_ws  = (bf*)(ws);                    // 32 MiB
  unsigned* xdbl  = (unsigned*)(ws + 33554432);   // 20 MiB
  bf*       xn_ws = (bf*)(ws + 54525952);         // 16 MiB
  __half*   hloc  = (__half*)(ws + 71303168);     // 16 MiB fp16 (NC=128; hin aliases after k4)
  __half*   ssum  = (__half*)(ws + 88080384);     // 1 MiB fp16 (total 89,128,960 B — known-good)
  (void)in_sizes; (void)n_in; (void)out_size; (void)ws_size;

  hipLaunchKernelGGL(k1_ln_conv, dim3(BB * NT), dim3(256), 0, stream,
                     input, ln_g, ln_b, in_proj_w, conv_w, conv_b, u_ws, xn_ws);
  hipLaunchKernelGGL(k2_xproj, dim3(1024), dim3(256), 0, stream,
                     u_ws, x_proj_w, xdbl);
  hipLaunchKernelGGL(k3_scanA, dim3(GG * NC / 4), dim3(256), 0, stream,
                     xdbl, u_ws, A_log, dt_proj_w, dt_proj_b, hloc, ssum);
  hipLaunchKernelGGL(k4_combine, dim3(GG), dim3(1024), 0, stream,
                     ssum, A_log, hloc);
  hipLaunchKernelGGL(k56_scan_final, dim3(BB * NC / 2), dim3(512), 0, stream,
                     xdbl, u_ws, A_log, dt_proj_w, dt_proj_b, Dw, hloc, xn_ws,
                     in_proj_w, out_proj_w, out);
}